// Round 1
// baseline (81.453 us; speedup 1.0000x reference)
//
#include <hip/hip_runtime.h>

#define NB    512
#define FEAT  21609   // 21*21*7*7
#define CHW   6272    // 128*49 floats per batch
#define PARTS 4       // channel split: blocks per batch
#define CPB   32      // channels per block (128/PARTS)
#define CELL  1568    // CPB*49 floats staged per block
#define V4B   392     // CELL/4
#define PLANE 1280    // CPB * 40-float padded block per j2-parity class

// 49 ij's grouped into 25 same-parity-class slots (pairs; slot 24 is a singleton).
// classes: (i&1,j&1)=ee 16, eo 12, oe 12, oo 9
__constant__ unsigned char c_pa[25] = {0,4,14,18,28,32,42,46,  1,5,17,29,33,45,
                                       7,11,21,25,35,39,       8,12,24,36,40};
__constant__ unsigned char c_pb[25] = {2,6,16,20,30,34,44,48,  3,15,19,31,43,47,
                                       9,13,23,27,37,41,       10,22,26,38,255};

__device__ __forceinline__ unsigned short f2bf(float x) {
    unsigned u = __float_as_uint(x);
    u += 0x7fffu + ((u >> 16) & 1u);   // round-to-nearest-even
    return (unsigned short)(u >> 16);
}
__device__ __forceinline__ float bf2f(unsigned short h) {
    return __uint_as_float((unsigned)h << 16);
}

// Setup: init out with bias; build the 784-entry f32 weight table into ws.
// table entry n = (4t+u)*49 + ij  ->  float4 {w0,w1,w2,w3} for (i2=(i&1)+2t, j2=(j&1)+2u)
__global__ __launch_bounds__(256) void setup_kernel(
    const float* __restrict__ w_bbox,
    const float* __restrict__ b_bbox,
    float* __restrict__ out,
    float4* __restrict__ wtab)
{
    const int tid = threadIdx.x, bid = blockIdx.x;
    int k = bid * 256 + tid;
    if (k < 4 * NB) out[k] = b_bbox[k & 3];

    int n = bid * 98 + tid;                 // 8 blocks x 98 = 784
    if (tid < 98 && n < 784) {
        int ij = n % 49, tu = n / 49;
        int t = tu >> 2, u = tu & 3;
        int i = ij / 7, j = ij - 7 * i;
        int i2 = (i & 1) + 2 * t, j2 = (j & 1) + 2 * u;
        float4 wq = make_float4(0.f, 0.f, 0.f, 0.f);
        if (i2 < 7 && j2 < 7) {
            int p = 10 + ((i2 - i) >> 1);
            int q = 10 + ((j2 - j) >> 1);
            int f = ((p * 21 + q) * 7 + i) * 7 + j;
            wq = make_float4(w_bbox[f], w_bbox[FEAT + f],
                             w_bbox[2 * FEAT + f], w_bbox[3 * FEAT + f]);
        }
        wtab[n] = wq;
    }
}

__global__ __launch_bounds__(256, 4) void corr_head_kernel(
    const float* __restrict__ patch1,
    const float* __restrict__ patch2,
    const float4* __restrict__ wtab,
    float* __restrict__ out)
{
    // s2p: value p2[c, 7*i2 + j2] at s2p[(j2&1)*PLANE + c*40 + i2*4 + (j2>>1)]
    // c-block 40 floats: i2=0..6 at [0,28), dummy i2=7 row [28,32) zeroed, [32,40) pad.
    __shared__ __align__(16) unsigned short s1b[CELL];      // p1 bf16, 3.1 KB
    __shared__ __align__(16) float          s2p[2 * PLANE]; // 10 KB
    __shared__ __align__(16) float4         s_wf[784];      // f32 w4 table, 12.25 KB
    __shared__ float s_red[16];

    const int tid  = threadIdx.x;
    const int b    = blockIdx.x >> 2;
    const int part = blockIdx.x & 3;

    const float4* g1 = (const float4*)(patch1 + (size_t)b * CHW + part * CELL);
    const float4* g2 = (const float4*)(patch2 + (size_t)b * CHW + part * CELL);

    // ---- issue ALL global loads up front (one exposed HBM latency) ----
    float4 A0 = g1[tid];
    float4 B0 = g2[tid];
    float4 A1, B1;
    const bool tail = tid < (V4B - 256);     // 136 threads
    if (tail) { A1 = g1[tid + 256]; B1 = g2[tid + 256]; }
    float4 W0 = wtab[tid];
    float4 W1 = wtab[tid + 256];
    float4 W2 = wtab[tid + 512];
    float4 W3;
    const bool wtail = tid < (784 - 768);    // 16 threads
    if (wtail) W3 = wtab[tid + 768];

    // ---- zero dummy-readable slots (independent of loads, hides latency) ----
    { int jp = tid >> 7, c = (tid >> 2) & 31, u = tid & 3;   // i2=7 dummy row, 256 slots
      s2p[jp * PLANE + c * 40 + 28 + u] = 0.f; }
    if (tid < 224) {                                          // odd-class j2=7 dummy column
        int c = tid / 7, i2 = tid - 7 * c;
        s2p[PLANE + c * 40 + i2 * 4 + 3] = 0.f;
    }

    // ---- LDS stores ----
    s_wf[tid]       = W0;
    s_wf[tid + 256] = W1;
    s_wf[tid + 512] = W2;
    if (wtail) s_wf[tid + 768] = W3;

    ((ushort4*)s1b)[tid] = make_ushort4(f2bf(A0.x), f2bf(A0.y), f2bf(A0.z), f2bf(A0.w));
    if (tail)
        ((ushort4*)s1b)[tid + 256] = make_ushort4(f2bf(A1.x), f2bf(A1.y), f2bf(A1.z), f2bf(A1.w));

    {   // p2 scatter into parity-split layout (~2-way banks)
        int e = tid * 4;
        int c = e / 49;
        int r = e - 49 * c;
        #pragma unroll
        for (int k2 = 0; k2 < 4; ++k2) {
            int i2 = (r * 37) >> 8;     // r/7 for r<49
            int j2 = r - 7 * i2;
            s2p[(j2 & 1) * PLANE + c * 40 + i2 * 4 + (j2 >> 1)] = (&B0.x)[k2];
            if (++r == 49) { r = 0; ++c; }
        }
    }
    if (tail) {
        int e = (tid + 256) * 4;
        int c = e / 49;
        int r = e - 49 * c;
        #pragma unroll
        for (int k2 = 0; k2 < 4; ++k2) {
            int i2 = (r * 37) >> 8;
            int j2 = r - 7 * i2;
            s2p[(j2 & 1) * PLANE + c * 40 + i2 * 4 + (j2 >> 1)] = (&B1.x)[k2];
            if (++r == 49) { r = 0; ++c; }
        }
    }
    __syncthreads();

    // ---- main: thread (slot = tid>>3 owns 2 same-class ij's, cs = tid&7 -> c = cs+8cc) ----
    float a0 = 0.f, a1 = 0.f, a2 = 0.f, a3 = 0.f;
    if (tid < 200) {
        const int slot = tid >> 3, cs = tid & 7;
        const int ija  = c_pa[slot];
        const int ijbr = c_pb[slot];
        const bool has_b = (ijbr < 49);
        const int ijb  = has_b ? ijbr : ija;     // safe reads; discarded at weighting
        const int i = ija / 7, j = ija - 7 * i;  // parity class shared by ija/ijb
        const float* base2 = s2p + (j & 1) * PLANE + (i & 1) * 4;

        float da[4][4], db[4][4];
        #pragma unroll
        for (int t = 0; t < 4; ++t)
            #pragma unroll
            for (int u = 0; u < 4; ++u) { da[t][u] = 0.f; db[t][u] = 0.f; }

        #pragma unroll
        for (int cc = 0; cc < 4; ++cc) {
            int c = cs + 8 * cc;                 // c in [0,32)
            float f1a = bf2f(s1b[c * 49 + ija]);
            float f1b = bf2f(s1b[c * 49 + ijb]);
            const float* bc = base2 + c * 40;
            #pragma unroll
            for (int t = 0; t < 4; ++t) {
                float4 f2 = *(const float4*)(bc + 8 * t);
                da[t][0] = fmaf(f1a, f2.x, da[t][0]);
                da[t][1] = fmaf(f1a, f2.y, da[t][1]);
                da[t][2] = fmaf(f1a, f2.z, da[t][2]);
                da[t][3] = fmaf(f1a, f2.w, da[t][3]);
                db[t][0] = fmaf(f1b, f2.x, db[t][0]);
                db[t][1] = fmaf(f1b, f2.y, db[t][1]);
                db[t][2] = fmaf(f1b, f2.z, db[t][2]);
                db[t][3] = fmaf(f1b, f2.w, db[t][3]);
            }
        }

        // ---- weighting (f32 weights, broadcast LDS reads across the 8 channel-lanes) ----
        #pragma unroll
        for (int t = 0; t < 4; ++t)
            #pragma unroll
            for (int u = 0; u < 4; ++u) {
                float4 wq = s_wf[(4 * t + u) * 49 + ija];
                float d = da[t][u];
                a0 = fmaf(d, wq.x, a0);
                a1 = fmaf(d, wq.y, a1);
                a2 = fmaf(d, wq.z, a2);
                a3 = fmaf(d, wq.w, a3);
            }
        if (has_b) {
            #pragma unroll
            for (int t = 0; t < 4; ++t)
                #pragma unroll
                for (int u = 0; u < 4; ++u) {
                    float4 wq = s_wf[(4 * t + u) * 49 + ijb];
                    float d = db[t][u];
                    a0 = fmaf(d, wq.x, a0);
                    a1 = fmaf(d, wq.y, a1);
                    a2 = fmaf(d, wq.z, a2);
                    a3 = fmaf(d, wq.w, a3);
                }
        }
    }

    // ---- reduce 256 threads -> 4 partials, atomically fold into out (bias pre-set) ----
    for (int off = 32; off > 0; off >>= 1) {
        a0 += __shfl_down(a0, off, 64);
        a1 += __shfl_down(a1, off, 64);
        a2 += __shfl_down(a2, off, 64);
        a3 += __shfl_down(a3, off, 64);
    }
    if ((tid & 63) == 0) {
        int w = tid >> 6;
        s_red[w * 4 + 0] = a0;
        s_red[w * 4 + 1] = a1;
        s_red[w * 4 + 2] = a2;
        s_red[w * 4 + 3] = a3;
    }
    __syncthreads();
    if (tid < 4) {
        float r = s_red[tid] + s_red[4 + tid] + s_red[8 + tid] + s_red[12 + tid];
        atomicAdd(&out[b * 4 + tid], r);
    }
}

extern "C" void kernel_launch(void* const* d_in, const int* in_sizes, int n_in,
                              void* d_out, int out_size, void* d_ws, size_t ws_size,
                              hipStream_t stream) {
    const float* patch1 = (const float*)d_in[0];
    const float* patch2 = (const float*)d_in[1];
    const float* w_bbox = (const float*)d_in[2];
    const float* b_bbox = (const float*)d_in[3];
    float* out = (float*)d_out;
    float4* wtab = (float4*)d_ws;   // 784 * 16 B = 12.25 KB of workspace

    setup_kernel<<<dim3(8), dim3(256), 0, stream>>>(w_bbox, b_bbox, out, wtab);
    corr_head_kernel<<<dim3(NB * PARTS), dim3(256), 0, stream>>>(patch1, patch2, wtab, out);
}